// Round 7
// baseline (295.939 us; speedup 1.0000x reference)
//
#include <hip/hip_runtime.h>
#include <hip/hip_bf16.h>

#define EPSF 1e-14f
#define RHOF 8.0f

typedef __attribute__((ext_vector_type(4))) float f32x4;
typedef __attribute__((ext_vector_type(8))) int   i32x8;

#define AS_GLOBAL __attribute__((address_space(1)))
#define AS_LDS    __attribute__((address_space(3)))

// fp8 packed layout, BK=128 (for mfma_scale 16x16x128). Tile = 128 rows x
// 128 cols fp8 = 16 KB = 1024 units of 16 B. Row r = 8 units; content unit
// u stored at slot u ^ (r&7). Fragment (quad qd) needs k-block qd*32..+31 =
// content units {2qd, 2qd+1} -> slots s0=(2qd)^(lo&7), s0^1.
// global_load_lds deposit order == packed order.

// One-pass prep: thread reads 16 contiguous fp32 (64 B), cvt_pk to 16 fp8,
// one 16-B store to the packed slot address. No LDS, no barrier.
__global__ __launch_bounds__(256) void prep_fp8(
    const float* __restrict__ im,  const float* __restrict__ tt,
    const float* __restrict__ rim, const float* __restrict__ rtt,
    unsigned char* __restrict__ bIm,  unsigned char* __restrict__ bTt,
    unsigned char* __restrict__ bRim, unsigned char* __restrict__ bRtt,
    float* __restrict__ S_im, float* __restrict__ S_tt,
    float* __restrict__ diag, float* __restrict__ red,
    int D, int bpm /* conversion blocks per matrix */)
{
    const int b = blockIdx.x;
    const int tid = threadIdx.x;
    const int nConv = 4 * bpm;
    if (b < nConv) {
        int mIdx = b / bpm;
        int blk  = b - mIdx * bpm;
        const float* src = (mIdx == 0) ? rim : (mIdx == 1) ? tt
                          : (mIdx == 2) ? rtt : im;
        unsigned char* dst = (mIdx == 0) ? bRim : (mIdx == 1) ? bTt
                            : (mIdx == 2) ? bRtt : bIm;
        const int upr = D >> 4;            // 16-B content units per row
        const int rpb = 256 / upr;         // rows per block (D=1024 -> 4)
        const int urow = tid / upr;
        const int c    = tid - urow * upr; // content unit within row
        const int r    = blk * rpb + urow;
        const int kTiles = D >> 7;
        const float* p = src + (size_t)r * D + (size_t)c * 16;
        float4 v0 = ((const float4*)p)[0];
        float4 v1 = ((const float4*)p)[1];
        float4 v2 = ((const float4*)p)[2];
        float4 v3 = ((const float4*)p)[3];
        int w0 = __builtin_amdgcn_cvt_pk_fp8_f32(v0.x, v0.y, 0, false);
        w0     = __builtin_amdgcn_cvt_pk_fp8_f32(v0.z, v0.w, w0, true);
        int w1 = __builtin_amdgcn_cvt_pk_fp8_f32(v1.x, v1.y, 0, false);
        w1     = __builtin_amdgcn_cvt_pk_fp8_f32(v1.z, v1.w, w1, true);
        int w2 = __builtin_amdgcn_cvt_pk_fp8_f32(v2.x, v2.y, 0, false);
        w2     = __builtin_amdgcn_cvt_pk_fp8_f32(v2.z, v2.w, w2, true);
        int w3 = __builtin_amdgcn_cvt_pk_fp8_f32(v3.x, v3.y, 0, false);
        w3     = __builtin_amdgcn_cvt_pk_fp8_f32(v3.z, v3.w, w3, true);
        int4 out = make_int4(w0, w1, w2, w3);
        const int kb = c >> 3;
        const int p8 = (c & 7) ^ (r & 7);          // XOR slot
        *(int4*)(dst + ((size_t)((r >> 7) * kTiles + kb) * 1024
                        + (size_t)(r & 127) * 8 + p8) * 16) = out;
    } else {
        int db = b - nConv;
        if (db == 0 && tid < 8) red[tid] = 0.f;
        if (tid < 4) { S_im[db * 4 + tid] = 0.f; S_tt[db * 4 + tid] = 0.f; }
        int row  = db * 4 + (tid >> 6);
        int lane = tid & 63;
        const float* a = rim + (size_t)row * D;
        const float* c2 = rtt + (size_t)row * D;
        float s = 0.f;
        for (int k = lane * 4; k < D; k += 256) {
            float4 av = *(const float4*)(a + k);
            float4 cv = *(const float4*)(c2 + k);
            s += av.x * cv.x + av.y * cv.y + av.z * cv.z + av.w * cv.w;
        }
        #pragma unroll
        for (int m2 = 1; m2 < 64; m2 <<= 1) s += __shfl_xor(s, m2, 64);
        if (lane == 0) diag[row] = s;
    }
}

// MX-scaled fp8 GEMM, 256x256 tile, 8 waves (2M x 4N), BK=128.
// A: DMA -> LDS (dbuf, 64 KB total) -- shared by 4 waves per M-half.
// B: global -> REGISTERS direct (8 KB/wave/K-tile = 32 VGPR), register
//    double-buffered across K-tiles, zero synchronization. Removes 1/3 of
//    LDS reads and 1/2 of DMA deposit traffic; LDS read (~1540 cyc/tile)
//    now well under MFMA pipe (~2214 cyc/tile/SIMD).
// z-merged: 256 fat blocks (1/CU); z1's tile-0 A-DMA + B-loads issue at
// z0's last K-tile and drain under z0's epilogue (kTiles even: parity ok).
// No intra-tile barriers (compiler-scheduled ds_read||MFMA region); tile
// boundary = per-wave vmcnt(0) on loads issued a full tile ago + s_barrier.
__global__ __launch_bounds__(512, 2) void gemm_expsum(
    const unsigned char* __restrict__ A0, const unsigned char* __restrict__ B0,
    float* __restrict__ S0,
    const unsigned char* __restrict__ A1, const unsigned char* __restrict__ B1,
    float* __restrict__ S1,
    const float* __restrict__ logit_scale, const int* __restrict__ offset,
    int Bn, int D)
{
    __shared__ unsigned char As[2][32768];   // A tile (2 x 128-row halves), dbuf

    const int tid  = threadIdx.x;
    const int wave = tid >> 6;
    const int lane = tid & 63;
    const int lo   = lane & 15;
    const int qd   = lane >> 4;
    const int wm   = wave >> 2;              // 0..1  (M half)
    const int wn   = wave & 3;               // 0..3  (N quarter)
    const int offA = ((2 * qd) ^ (lo & 7)) * 16;   // first 16-B slot

    // XCD-bijective swizzle (nwg = 256, % 8 == 0).
    const int nx  = gridDim.x;
    const int nwg = nx * gridDim.y;
    int wg = blockIdx.y * nx + blockIdx.x;
    int swz = ((nwg & 7) == 0) ? ((wg & 7) * (nwg >> 3) + (wg >> 3)) : wg;
    const int by = swz / nx;
    const int bx = swz - by * nx;

    const int kTiles = D >> 7;

    // A staging: wave w stages bytes [w*4096, w*4096+4096) of the 32 KB
    // A tile (halves stored consecutively: w*4096 = (w>>2)*16384+(w&3)*4096).
    const int sh = wave >> 2;
    const int sq = wave & 3;
    auto stageA = [&](int buf, const unsigned char* At, int kb) {
        const unsigned char* g = At + ((size_t)sh * kTiles + kb) * 16384
                               + sq * 4096 + lane * 16;
        #pragma unroll
        for (int q = 0; q < 4; ++q)
            __builtin_amdgcn_global_load_lds(
                (const AS_GLOBAL unsigned int*)(g + q * 1024),
                (AS_LDS unsigned int*)&As[buf][wave * 4096 + q * 1024],
                16, 0, 0);
    };

    // B direct-to-register: per (tj, k-half) fragment, two dwordx4 at the
    // packed XOR-slot addresses (same math as the old LDS read, but global).
    const size_t bRowOff = (size_t)(((wn & 1) * 64 + lo) * 128 + offA);
    auto loadB = [&](i32x8* dst, const unsigned char* Bt, int kb) {
        const unsigned char* g = Bt + ((size_t)(wn >> 1) * kTiles + kb) * 16384
                               + bRowOff;
        #pragma unroll
        for (int tj = 0; tj < 4; ++tj) {
            union { int4 h[2]; i32x8 v; } u;
            const unsigned char* gp = g + tj * 2048;
            u.h[0] = *(const int4*)gp;
            u.h[1] = *(const int4*)((const unsigned char*)((size_t)gp ^ 16));
            dst[tj] = u.v;
        }
    };

    // per-lane LDS A fragment base (r&7 == lo&7 for all ti)
    const int aOff0 = wm * 16384 + lo * 128 + offA;                 // + ti*2048

    const float ls = logit_scale[0];
    const int offs = offset[0];

    i32x8 bq[4], bqN[4];

    for (int zz = 0; zz < 2; ++zz) {
        const unsigned char* A = zz ? A1 : A0;
        const unsigned char* B = zz ? B1 : B0;
        float* S = zz ? S1 : S0;
        const unsigned char* Atile = A + (size_t)(2 * by) * kTiles * 16384;
        const unsigned char* Btile = B + (size_t)(2 * bx) * kTiles * 16384;

        f32x4 acc[8][4];
        #pragma unroll
        for (int i = 0; i < 8; ++i)
            #pragma unroll
            for (int j = 0; j < 4; ++j)
                acc[i][j] = (f32x4){0.f, 0.f, 0.f, 0.f};

        if (zz == 0) {                       // cold prologue (z0 only)
            stageA(0, Atile, 0);
            loadB(bq, Btile, 0);
            asm volatile("s_waitcnt vmcnt(0)" ::: "memory");
            __builtin_amdgcn_s_barrier();
        }
        // zz==1: A tile0 staged + B tile0 loaded during z0's last K-tile,
        // drained under z0's epilogue; A sits in buf0 (kTiles even).

        for (int kb = 0; kb < kTiles; ++kb) {
            const int cur = kb & 1;
            if (kb + 1 < kTiles) {
                stageA(1 - cur, Atile, kb + 1);
                loadB(bqN, Btile, kb + 1);
            } else if (zz == 0) {            // last z0 tile: stage z1 tile0
                stageA(1 - cur, A1 + (size_t)(2 * by) * kTiles * 16384, 0);
                loadB(bqN, B1 + (size_t)(2 * bx) * kTiles * 16384, 0);
            }

            // One scheduler region: 16 ds_read_b128 (A frags) + 32 MFMA;
            // B operands already in registers.
            #pragma unroll
            for (int ph = 0; ph < 4; ++ph) {
                const int ti0 = 2 * ph;
                union { int4 h[2]; i32x8 v; } ua0, ua1;
                {
                    const int aa0 = aOff0 + ti0 * 2048;
                    ua0.h[0] = *(const int4*)&As[cur][aa0];
                    ua0.h[1] = *(const int4*)&As[cur][aa0 ^ 16];
                    const int aa1 = aOff0 + (ti0 + 1) * 2048;
                    ua1.h[0] = *(const int4*)&As[cur][aa1];
                    ua1.h[1] = *(const int4*)&As[cur][aa1 ^ 16];
                }
                #pragma unroll
                for (int tj = 0; tj < 4; ++tj)
                    acc[ti0][tj] = __builtin_amdgcn_mfma_scale_f32_16x16x128_f8f6f4(
                        ua0.v, bq[tj], acc[ti0][tj],
                        0, 0, 0, 127, 0, 127);
                #pragma unroll
                for (int tj = 0; tj < 4; ++tj)
                    acc[ti0 + 1][tj] = __builtin_amdgcn_mfma_scale_f32_16x16x128_f8f6f4(
                        ua1.v, bq[tj], acc[ti0 + 1][tj],
                        0, 0, 0, 127, 0, 127);
            }

            if (kb + 1 < kTiles) {
                // own A-DMA + B-loads for kb+1 issued a full tile ago
                asm volatile("s_waitcnt vmcnt(0)" ::: "memory");
                __builtin_amdgcn_s_barrier();
            }
            if (kb + 1 < kTiles || zz == 0) {
                #pragma unroll
                for (int j = 0; j < 4; ++j) bq[j] = bqN[j];
            }
        }

        // epilogue for this z; z1's tile-0 loads (if zz==0) fly under it
        const int rowBase = by * 256 + wm * 128;
        const int colBase = bx * 256 + wn * 64;
        #pragma unroll
        for (int ti = 0; ti < 8; ++ti) {
            #pragma unroll
            for (int r = 0; r < 4; ++r) {
                int gi = rowBase + 16 * ti + 4 * qd + r; // C/D row=quad*4+reg
                float rs = 0.f;
                #pragma unroll
                for (int tj = 0; tj < 4; ++tj) {
                    int gj = colBase + 16 * tj + lo;     // C/D col=lane&15
                    float e = __expf(ls * acc[ti][tj][r]);
                    if (gj == gi + offs) e = 0.f;        // shifted diagonal
                    rs += e;
                }
                #pragma unroll
                for (int m = 1; m < 16; m <<= 1) rs += __shfl_xor(rs, m, 64);
                if (lo == 0) atomicAdd(&S[gi], rs);
            }
        }

        if (zz == 0) {                       // drain z1 tile0 before z1 loop
            asm volatile("s_waitcnt vmcnt(0)" ::: "memory");
            __builtin_amdgcn_s_barrier();
        }
    }
}

// 32-block reduction; last block (ticket) computes the scalar loss.
__global__ __launch_bounds__(256) void final_kernel(
    const float* __restrict__ S_im, const float* __restrict__ S_tt,
    const float* __restrict__ diag,
    const float* __restrict__ ru_im, const float* __restrict__ ru_tt,
    const float* __restrict__ l1_im, const float* __restrict__ l1_tt,
    const float* __restrict__ u_im,  const float* __restrict__ u_tt,
    const float* __restrict__ logit_scale, float* __restrict__ red,
    float* __restrict__ out, int Bn)
{
    const float ls = logit_scale[0];
    const float inv_rw = 1.0f / (float)(Bn - 1);
    const int gid = blockIdx.x * 256 + threadIdx.x;
    const int stride = gridDim.x * 256;
    float pg = 0.f, lg = 0.f;
    for (int i = gid; i < Bn; i += stride) {
        float p1 = l1_im[i] / (u_im[i] + EPSF) + l1_tt[i] / (u_tt[i] + EPSF);
        float dd = expf(-ls * diag[i]);
        float p2 = dd * S_im[i] * inv_rw / (ru_im[i] + EPSF)
                 + dd * S_tt[i] * inv_rw / (ru_tt[i] + EPSF);
        pg += p1 + p2;
        lg += logf(u_im[i]) + logf(u_tt[i]);
    }
    __shared__ float sp[256], sl[256];
    sp[threadIdx.x] = pg; sl[threadIdx.x] = lg;
    __syncthreads();
    for (int s = 128; s > 0; s >>= 1) {
        if (threadIdx.x < s) { sp[threadIdx.x] += sp[threadIdx.x + s];
                               sl[threadIdx.x] += sl[threadIdx.x + s]; }
        __syncthreads();
    }
    if (threadIdx.x == 0) {
        atomicAdd(&red[0], sp[0]);
        atomicAdd(&red[1], sl[0]);
        __threadfence();
        int t = atomicAdd((int*)&red[2], 1);
        if (t == gridDim.x - 1) {
            float pgSum = atomicAdd(&red[0], 0.f);
            float lgSum = atomicAdd(&red[1], 0.f);
            float loss = ((pgSum / (float)Bn) * 0.5f) / ls
                       + RHOF / ls
                       + (lgSum / (float)Bn) * 0.5f / ls;
            out[0] = loss;
        }
    }
}

extern "C" void kernel_launch(void* const* d_in, const int* in_sizes, int n_in,
                              void* d_out, int out_size, void* d_ws, size_t ws_size,
                              hipStream_t stream) {
    const float* im    = (const float*)d_in[0];
    const float* tt    = (const float*)d_in[1];
    const float* rim   = (const float*)d_in[2];
    const float* rtt   = (const float*)d_in[3];
    const float* ru_im = (const float*)d_in[4];
    const float* ru_tt = (const float*)d_in[5];
    const float* l1_im = (const float*)d_in[6];
    const float* l1_tt = (const float*)d_in[7];
    const float* u_im  = (const float*)d_in[8];
    const float* u_tt  = (const float*)d_in[9];
    const float* lsc   = (const float*)d_in[10];
    const int*   offs  = (const int*)d_in[11];

    const int Bn = in_sizes[4];          // 4096
    const int D  = in_sizes[0] / Bn;     // 1024
    const int rpb = 4096 / D;            // rows per conversion block
    const int bpm = Bn / rpb;            // conversion blocks per matrix

    char* base = (char*)d_ws;
    float* S_im = (float*)base;
    float* S_tt = S_im + Bn;
    float* diag = S_tt + Bn;
    float* red  = diag + Bn;             // [0]=pg, [1]=lg, [2]=ticket
    const size_t headBytes = (((size_t)(3 * Bn + 8) * sizeof(float)) + 255) & ~(size_t)255;
    const size_t matBytes  = (size_t)Bn * D;          // fp8: 1 B/elem
    unsigned char* buf0 = (unsigned char*)(base + headBytes);
    unsigned char* bRim = buf0;
    unsigned char* bTt  = buf0 + matBytes;
    unsigned char* bRtt = buf0 + 2 * matBytes;
    unsigned char* bIm  = buf0 + 3 * matBytes;

    prep_fp8<<<4 * bpm + Bn / 4, 256, 0, stream>>>(
        im, tt, rim, rtt, bIm, bTt, bRim, bRtt, S_im, S_tt, diag, red, D, bpm);

    dim3 ggrid(Bn / 256, Bn / 256, 1);
    gemm_expsum<<<ggrid, 512, 0, stream>>>(bRim, bTt, S_im, bRtt, bIm, S_tt,
                                           lsc, offs, Bn, D);

    final_kernel<<<32, 256, 0, stream>>>(S_im, S_tt, diag, ru_im, ru_tt,
                                         l1_im, l1_tt, u_im, u_tt, lsc,
                                         red, (float*)d_out, Bn);
}

// Round 8
// 180.142 us; speedup vs baseline: 1.6428x; 1.6428x over previous
//
#include <hip/hip_runtime.h>
#include <hip/hip_bf16.h>

#define EPSF 1e-14f
#define RHOF 8.0f

typedef __attribute__((ext_vector_type(4))) float f32x4;
typedef __attribute__((ext_vector_type(8))) int   i32x8;

#define AS_GLOBAL __attribute__((address_space(1)))
#define AS_LDS    __attribute__((address_space(3)))

// fp8 packed layout, BK=128 (for mfma_scale 16x16x128). Tile = 128 rows x
// 128 cols fp8 = 16 KB = 1024 units of 16 B. Row r = 8 units; content unit
// u stored at slot u ^ (r&7). Fragment (quad qd) needs k-block qd*32..+31 =
// content units {2qd, 2qd+1} -> slots s0=(2qd)^(lo&7), s0^1.
// global_load_lds deposit order == packed order.

// One-pass prep: thread reads 16 contiguous fp32 (64 B), cvt_pk to 16 fp8,
// one 16-B store to the packed slot address. No LDS, no barrier.
__global__ __launch_bounds__(256) void prep_fp8(
    const float* __restrict__ im,  const float* __restrict__ tt,
    const float* __restrict__ rim, const float* __restrict__ rtt,
    unsigned char* __restrict__ bIm,  unsigned char* __restrict__ bTt,
    unsigned char* __restrict__ bRim, unsigned char* __restrict__ bRtt,
    float* __restrict__ S_im, float* __restrict__ S_tt,
    float* __restrict__ diag, float* __restrict__ red,
    int D, int bpm /* conversion blocks per matrix */)
{
    const int b = blockIdx.x;
    const int tid = threadIdx.x;
    const int nConv = 4 * bpm;
    if (b < nConv) {
        int mIdx = b / bpm;
        int blk  = b - mIdx * bpm;
        const float* src = (mIdx == 0) ? rim : (mIdx == 1) ? tt
                          : (mIdx == 2) ? rtt : im;
        unsigned char* dst = (mIdx == 0) ? bRim : (mIdx == 1) ? bTt
                            : (mIdx == 2) ? bRtt : bIm;
        const int upr = D >> 4;            // 16-B content units per row
        const int rpb = 256 / upr;         // rows per block (D=1024 -> 4)
        const int urow = tid / upr;
        const int c    = tid - urow * upr; // content unit within row
        const int r    = blk * rpb + urow;
        const int kTiles = D >> 7;
        const float* p = src + (size_t)r * D + (size_t)c * 16;
        float4 v0 = ((const float4*)p)[0];
        float4 v1 = ((const float4*)p)[1];
        float4 v2 = ((const float4*)p)[2];
        float4 v3 = ((const float4*)p)[3];
        int w0 = __builtin_amdgcn_cvt_pk_fp8_f32(v0.x, v0.y, 0, false);
        w0     = __builtin_amdgcn_cvt_pk_fp8_f32(v0.z, v0.w, w0, true);
        int w1 = __builtin_amdgcn_cvt_pk_fp8_f32(v1.x, v1.y, 0, false);
        w1     = __builtin_amdgcn_cvt_pk_fp8_f32(v1.z, v1.w, w1, true);
        int w2 = __builtin_amdgcn_cvt_pk_fp8_f32(v2.x, v2.y, 0, false);
        w2     = __builtin_amdgcn_cvt_pk_fp8_f32(v2.z, v2.w, w2, true);
        int w3 = __builtin_amdgcn_cvt_pk_fp8_f32(v3.x, v3.y, 0, false);
        w3     = __builtin_amdgcn_cvt_pk_fp8_f32(v3.z, v3.w, w3, true);
        int4 out = make_int4(w0, w1, w2, w3);
        const int kb = c >> 3;
        const int p8 = (c & 7) ^ (r & 7);          // XOR slot
        *(int4*)(dst + ((size_t)((r >> 7) * kTiles + kb) * 1024
                        + (size_t)(r & 127) * 8 + p8) * 16) = out;
    } else {
        int db = b - nConv;
        if (db == 0 && tid < 8) red[tid] = 0.f;
        if (tid < 4) { S_im[db * 4 + tid] = 0.f; S_tt[db * 4 + tid] = 0.f; }
        int row  = db * 4 + (tid >> 6);
        int lane = tid & 63;
        const float* a = rim + (size_t)row * D;
        const float* c2 = rtt + (size_t)row * D;
        float s = 0.f;
        for (int k = lane * 4; k < D; k += 256) {
            float4 av = *(const float4*)(a + k);
            float4 cv = *(const float4*)(c2 + k);
            s += av.x * cv.x + av.y * cv.y + av.z * cv.z + av.w * cv.w;
        }
        #pragma unroll
        for (int m2 = 1; m2 < 64; m2 <<= 1) s += __shfl_xor(s, m2, 64);
        if (lane == 0) diag[row] = s;
    }
}

// MX-scaled fp8 GEMM, 256x256 tile, 8 waves (2M x 4N), BK=128.
// DEPTH-2 pipeline (T4 counted vmcnt):
//   A: DMA -> LDS, TRIPLE buffered (3 x 32 KB): A(g+2) issues at tile-g top
//      -> 2 full tiles of deposit-latency budget.
//   B: global -> named registers (no arrays-through-pointers: round-7's
//      scratch-spill bug), B(g+1) issued at tile-g top, swapped at boundary.
//   Boundary: vmcnt(4) leaves exactly A(g+2)'s 4 DMAs in flight (issue
//      order B(g+1) then A(g+2); FIFO => <=4 outstanding means A(g+1) and
//      B(g+1) are complete). vmcnt(0) only at the final boundary.
// Unified g=0..2*kTiles-1 loop covers both z GEMMs (z = g/kTiles);
// epilogue at each z's last tile, staging continues across it.
__global__ __launch_bounds__(512, 2) void gemm_expsum(
    const unsigned char* __restrict__ A0, const unsigned char* __restrict__ B0,
    float* __restrict__ S0,
    const unsigned char* __restrict__ A1, const unsigned char* __restrict__ B1,
    float* __restrict__ S1,
    const float* __restrict__ logit_scale, const int* __restrict__ offset,
    int Bn, int D)
{
    __shared__ unsigned char As[3][32768];   // A tile, triple-buffered

    const int tid  = threadIdx.x;
    const int wave = tid >> 6;
    const int lane = tid & 63;
    const int lo   = lane & 15;
    const int qd   = lane >> 4;
    const int wm   = wave >> 2;              // 0..1  (M half)
    const int wn   = wave & 3;               // 0..3  (N quarter)
    const int offA = ((2 * qd) ^ (lo & 7)) * 16;   // first 16-B slot

    // XCD-bijective swizzle (nwg = 256, % 8 == 0).
    const int nx  = gridDim.x;
    const int nwg = nx * gridDim.y;
    int wg = blockIdx.y * nx + blockIdx.x;
    int swz = ((nwg & 7) == 0) ? ((wg & 7) * (nwg >> 3) + (wg >> 3)) : wg;
    const int by = swz / nx;
    const int bx = swz - by * nx;

    const int kTiles = D >> 7;
    const int last = 2 * kTiles - 1;

    const unsigned char* Apan[2] = { A0 + (size_t)(2 * by) * kTiles * 16384,
                                     A1 + (size_t)(2 * by) * kTiles * 16384 };
    const unsigned char* Bpan[2] = { B0 + (size_t)(2 * bx) * kTiles * 16384,
                                     B1 + (size_t)(2 * bx) * kTiles * 16384 };
    float* Sarr[2] = { S0, S1 };

    // A staging: wave w stages bytes [w*4096, +4096) of the 32 KB A tile
    // (halves consecutive: waves 0-3 -> rows 0-127, waves 4-7 -> 128-255).
    const int sh = wave >> 2;
    const int sq = wave & 3;
    auto stageA = [&](int slot, int gi) {
        const int zi = (gi >= kTiles) ? 1 : 0;
        const int ki = gi - (zi ? kTiles : 0);
        const unsigned char* g = Apan[zi]
            + ((size_t)sh * kTiles + ki) * 16384 + sq * 4096 + lane * 16;
        unsigned char* l = &As[slot][wave * 4096];
        #pragma unroll
        for (int q = 0; q < 4; ++q)
            __builtin_amdgcn_global_load_lds(
                (const AS_GLOBAL unsigned int*)(g + q * 1024),
                (AS_LDS unsigned int*)(l + q * 1024), 16, 0, 0);
    };

    // B fragment global addresses: identical math to the old LDS read of
    // the packed tile, applied to the global tile base (identity deposit).
    const size_t bRowOff = (size_t)(((wn & 1) * 64 + lo) * 128 + offA);

#define LDB2(dst, p) do { union { int4 h[2]; i32x8 v; } _u;                  \
        _u.h[0] = *(const int4*)(p);                                         \
        _u.h[1] = *(const int4*)((const unsigned char*)((size_t)(p) ^ 16));  \
        dst = _u.v; } while (0)
#define LOADB4(b0_, b1_, b2_, b3_, gi) do {                                  \
        const int _zi = ((gi) >= kTiles) ? 1 : 0;                            \
        const int _ki = (gi) - (_zi ? kTiles : 0);                           \
        const unsigned char* _bp = Bpan[_zi]                                 \
            + ((size_t)(wn >> 1) * kTiles + _ki) * 16384 + bRowOff;          \
        LDB2(b0_, _bp);        LDB2(b1_, _bp + 2048);                        \
        LDB2(b2_, _bp + 4096); LDB2(b3_, _bp + 6144); } while (0)

#define MFMA4(ti, ua) do {                                                   \
        acc[ti][0] = __builtin_amdgcn_mfma_scale_f32_16x16x128_f8f6f4(       \
            (ua), bq0, acc[ti][0], 0, 0, 0, 127, 0, 127);                    \
        acc[ti][1] = __builtin_amdgcn_mfma_scale_f32_16x16x128_f8f6f4(       \
            (ua), bq1, acc[ti][1], 0, 0, 0, 127, 0, 127);                    \
        acc[ti][2] = __builtin_amdgcn_mfma_scale_f32_16x16x128_f8f6f4(       \
            (ua), bq2, acc[ti][2], 0, 0, 0, 127, 0, 127);                    \
        acc[ti][3] = __builtin_amdgcn_mfma_scale_f32_16x16x128_f8f6f4(       \
            (ua), bq3, acc[ti][3], 0, 0, 0, 127, 0, 127); } while (0)

    // per-lane LDS A fragment base (r&7 == lo&7 for all ti)
    const int aOff0 = wm * 16384 + lo * 128 + offA;              // + ti*2048

    const float ls = logit_scale[0];
    const int offs = offset[0];

    f32x4 acc[8][4];
    #pragma unroll
    for (int i = 0; i < 8; ++i)
        #pragma unroll
        for (int j = 0; j < 4; ++j)
            acc[i][j] = (f32x4){0.f, 0.f, 0.f, 0.f};

    i32x8 bq0, bq1, bq2, bq3, bn0, bn1, bn2, bn3;

    // Prologue: B(0) -> bq, A(0) -> slot0, A(1) -> slot1.
    // FIFO [B0:8, A0:4, A1:4]; vmcnt(4) => B0 + A0 complete, A1 in flight.
    LOADB4(bq0, bq1, bq2, bq3, 0);
    stageA(0, 0);
    stageA(1, 1);
    asm volatile("s_waitcnt vmcnt(4)" ::: "memory");
    __builtin_amdgcn_s_barrier();

    for (int g = 0; g <= last; ++g) {
        if (g + 1 <= last) LOADB4(bn0, bn1, bn2, bn3, g + 1);
        if (g + 2 <= last) stageA((g + 2) % 3, g + 2);

        // Compute tile g: A from LDS slot g%3, B from registers.
        {
            const unsigned char* Ab = &As[g % 3][0];
            #pragma unroll
            for (int ph = 0; ph < 4; ++ph) {
                const int ti0 = 2 * ph;
                union { int4 h[2]; i32x8 v; } ua0, ua1;
                const int aa0 = aOff0 + ti0 * 2048;
                ua0.h[0] = *(const int4*)&Ab[aa0];
                ua0.h[1] = *(const int4*)&Ab[aa0 ^ 16];
                const int aa1 = aOff0 + (ti0 + 1) * 2048;
                ua1.h[0] = *(const int4*)&Ab[aa1];
                ua1.h[1] = *(const int4*)&Ab[aa1 ^ 16];
                MFMA4(ti0, ua0.v);
                MFMA4(ti0 + 1, ua1.v);
            }
        }

        // z epilogue at each GEMM's last tile (staging flies under it).
        if ((g & (kTiles - 1)) == (kTiles - 1)) {
            const int z = (g >= kTiles) ? 1 : 0;
            float* S = Sarr[z];
            const int rowBase = by * 256 + wm * 128;
            const int colBase = bx * 256 + wn * 64;
            #pragma unroll
            for (int ti = 0; ti < 8; ++ti) {
                #pragma unroll
                for (int r = 0; r < 4; ++r) {
                    int gi = rowBase + 16 * ti + 4 * qd + r;
                    float rs = 0.f;
                    #pragma unroll
                    for (int tj = 0; tj < 4; ++tj) {
                        int gj = colBase + 16 * tj + lo;
                        float e = __expf(ls * acc[ti][tj][r]);
                        if (gj == gi + offs) e = 0.f;    // shifted diagonal
                        rs += e;
                    }
                    #pragma unroll
                    for (int m = 1; m < 16; m <<= 1) rs += __shfl_xor(rs, m, 64);
                    if (lo == 0) atomicAdd(&S[gi], rs);
                }
            }
            if (z == 0) {
                #pragma unroll
                for (int i = 0; i < 8; ++i)
                    #pragma unroll
                    for (int j = 0; j < 4; ++j)
                        acc[i][j] = (f32x4){0.f, 0.f, 0.f, 0.f};
            }
        }

        // Boundary: counted wait. Need A(g+1) (issued at g-1 top) and
        // B(g+1) (issued at g top) complete; A(g+2)'s 4 DMAs (newest) may
        // stay in flight -> vmcnt(4). Final boundary: nothing newer ->
        // vmcnt(0) (its loads are 2 tiles old -> cheap).
        if (g < last - 1) {
            asm volatile("s_waitcnt vmcnt(4)" ::: "memory");
        } else if (g == last - 1) {
            asm volatile("s_waitcnt vmcnt(0)" ::: "memory");
        }
        if (g < last) {
            __builtin_amdgcn_s_barrier();
            bq0 = bn0; bq1 = bn1; bq2 = bn2; bq3 = bn3;
        }
    }
#undef LDB2
#undef LOADB4
#undef MFMA4
}

// 32-block reduction; last block (ticket) computes the scalar loss.
__global__ __launch_bounds__(256) void final_kernel(
    const float* __restrict__ S_im, const float* __restrict__ S_tt,
    const float* __restrict__ diag,
    const float* __restrict__ ru_im, const float* __restrict__ ru_tt,
    const float* __restrict__ l1_im, const float* __restrict__ l1_tt,
    const float* __restrict__ u_im,  const float* __restrict__ u_tt,
    const float* __restrict__ logit_scale, float* __restrict__ red,
    float* __restrict__ out, int Bn)
{
    const float ls = logit_scale[0];
    const float inv_rw = 1.0f / (float)(Bn - 1);
    const int gid = blockIdx.x * 256 + threadIdx.x;
    const int stride = gridDim.x * 256;
    float pg = 0.f, lg = 0.f;
    for (int i = gid; i < Bn; i += stride) {
        float p1 = l1_im[i] / (u_im[i] + EPSF) + l1_tt[i] / (u_tt[i] + EPSF);
        float dd = expf(-ls * diag[i]);
        float p2 = dd * S_im[i] * inv_rw / (ru_im[i] + EPSF)
                 + dd * S_tt[i] * inv_rw / (ru_tt[i] + EPSF);
        pg += p1 + p2;
        lg += logf(u_im[i]) + logf(u_tt[i]);
    }
    __shared__ float sp[256], sl[256];
    sp[threadIdx.x] = pg; sl[threadIdx.x] = lg;
    __syncthreads();
    for (int s = 128; s > 0; s >>= 1) {
        if (threadIdx.x < s) { sp[threadIdx.x] += sp[threadIdx.x + s];
                               sl[threadIdx.x] += sl[threadIdx.x + s]; }
        __syncthreads();
    }
    if (threadIdx.x == 0) {
        atomicAdd(&red[0], sp[0]);
        atomicAdd(&red[1], sl[0]);
        __threadfence();
        int t = atomicAdd((int*)&red[2], 1);
        if (t == gridDim.x - 1) {
            float pgSum = atomicAdd(&red[0], 0.f);
            float lgSum = atomicAdd(&red[1], 0.f);
            float loss = ((pgSum / (float)Bn) * 0.5f) / ls
                       + RHOF / ls
                       + (lgSum / (float)Bn) * 0.5f / ls;
            out[0] = loss;
        }
    }
}

extern "C" void kernel_launch(void* const* d_in, const int* in_sizes, int n_in,
                              void* d_out, int out_size, void* d_ws, size_t ws_size,
                              hipStream_t stream) {
    const float* im    = (const float*)d_in[0];
    const float* tt    = (const float*)d_in[1];
    const float* rim   = (const float*)d_in[2];
    const float* rtt   = (const float*)d_in[3];
    const float* ru_im = (const float*)d_in[4];
    const float* ru_tt = (const float*)d_in[5];
    const float* l1_im = (const float*)d_in[6];
    const float* l1_tt = (const float*)d_in[7];
    const float* u_im  = (const float*)d_in[8];
    const float* u_tt  = (const float*)d_in[9];
    const float* lsc   = (const float*)d_in[10];
    const int*   offs  = (const int*)d_in[11];

    const int Bn = in_sizes[4];          // 4096
    const int D  = in_sizes[0] / Bn;     // 1024
    const int rpb = 4096 / D;            // rows per conversion block
    const int bpm = Bn / rpb;            // conversion blocks per matrix

    char* base = (char*)d_ws;
    float* S_im = (float*)base;
    float* S_tt = S_im + Bn;
    float* diag = S_tt + Bn;
    float* red  = diag + Bn;             // [0]=pg, [1]=lg, [2]=ticket
    const size_t headBytes = (((size_t)(3 * Bn + 8) * sizeof(float)) + 255) & ~(size_t)255;
    const size_t matBytes  = (size_t)Bn * D;          // fp8: 1 B/elem
    unsigned char* buf0 = (unsigned char*)(base + headBytes);
    unsigned char* bRim = buf0;
    unsigned char* bTt  = buf0 + matBytes;
    unsigned char* bRtt = buf0 + 2 * matBytes;
    unsigned char* bIm  = buf0 + 3 * matBytes;

    prep_fp8<<<4 * bpm + Bn / 4, 256, 0, stream>>>(
        im, tt, rim, rtt, bIm, bTt, bRim, bRtt, S_im, S_tt, diag, red, D, bpm);

    dim3 ggrid(Bn / 256, Bn / 256, 1);
    gemm_expsum<<<ggrid, 512, 0, stream>>>(bRim, bTt, S_im, bRtt, bIm, S_tt,
                                           lsc, offs, Bn, D);

    final_kernel<<<32, 256, 0, stream>>>(S_im, S_tt, diag, ru_im, ru_tt,
                                         l1_im, l1_tt, u_im, u_tt, lsc,
                                         red, (float*)d_out, Bn);
}

// Round 9
// 178.200 us; speedup vs baseline: 1.6607x; 1.0109x over previous
//
#include <hip/hip_runtime.h>
#include <hip/hip_bf16.h>

#define EPSF 1e-14f
#define RHOF 8.0f

typedef __attribute__((ext_vector_type(4))) float f32x4;
typedef __attribute__((ext_vector_type(8))) int   i32x8;

#define AS_GLOBAL __attribute__((address_space(1)))
#define AS_LDS    __attribute__((address_space(3)))

// fp8 packed layout, BK=128 (for mfma_scale 16x16x128). Tile = 128 rows x
// 128 cols fp8 = 16 KB = 1024 units of 16 B. Row r = 8 units; content unit
// u stored at slot u ^ (r&7). Fragment (quad qd) needs k-block qd*32..+31 =
// content units {2qd, 2qd+1} -> slots s0=(2qd)^(lo&7), s0^1.
// global_load_lds deposit order == packed order.

// One-pass prep: thread reads 16 contiguous fp32 (64 B), cvt_pk to 16 fp8,
// one 16-B store to the packed slot address. No LDS, no barrier.
__global__ __launch_bounds__(256) void prep_fp8(
    const float* __restrict__ im,  const float* __restrict__ tt,
    const float* __restrict__ rim, const float* __restrict__ rtt,
    unsigned char* __restrict__ bIm,  unsigned char* __restrict__ bTt,
    unsigned char* __restrict__ bRim, unsigned char* __restrict__ bRtt,
    float* __restrict__ S_im, float* __restrict__ S_tt,
    float* __restrict__ diag, float* __restrict__ red,
    int D, int bpm /* conversion blocks per matrix */)
{
    const int b = blockIdx.x;
    const int tid = threadIdx.x;
    const int nConv = 4 * bpm;
    if (b < nConv) {
        int mIdx = b / bpm;
        int blk  = b - mIdx * bpm;
        const float* src = (mIdx == 0) ? rim : (mIdx == 1) ? tt
                          : (mIdx == 2) ? rtt : im;
        unsigned char* dst = (mIdx == 0) ? bRim : (mIdx == 1) ? bTt
                            : (mIdx == 2) ? bRtt : bIm;
        const int upr = D >> 4;            // 16-B content units per row
        const int rpb = 256 / upr;         // rows per block (D=1024 -> 4)
        const int urow = tid / upr;
        const int c    = tid - urow * upr; // content unit within row
        const int r    = blk * rpb + urow;
        const int kTiles = D >> 7;
        const float* p = src + (size_t)r * D + (size_t)c * 16;
        float4 v0 = ((const float4*)p)[0];
        float4 v1 = ((const float4*)p)[1];
        float4 v2 = ((const float4*)p)[2];
        float4 v3 = ((const float4*)p)[3];
        int w0 = __builtin_amdgcn_cvt_pk_fp8_f32(v0.x, v0.y, 0, false);
        w0     = __builtin_amdgcn_cvt_pk_fp8_f32(v0.z, v0.w, w0, true);
        int w1 = __builtin_amdgcn_cvt_pk_fp8_f32(v1.x, v1.y, 0, false);
        w1     = __builtin_amdgcn_cvt_pk_fp8_f32(v1.z, v1.w, w1, true);
        int w2 = __builtin_amdgcn_cvt_pk_fp8_f32(v2.x, v2.y, 0, false);
        w2     = __builtin_amdgcn_cvt_pk_fp8_f32(v2.z, v2.w, w2, true);
        int w3 = __builtin_amdgcn_cvt_pk_fp8_f32(v3.x, v3.y, 0, false);
        w3     = __builtin_amdgcn_cvt_pk_fp8_f32(v3.z, v3.w, w3, true);
        int4 out = make_int4(w0, w1, w2, w3);
        const int kb = c >> 3;
        const int p8 = (c & 7) ^ (r & 7);          // XOR slot
        *(int4*)(dst + ((size_t)((r >> 7) * kTiles + kb) * 1024
                        + (size_t)(r & 127) * 8 + p8) * 16) = out;
    } else {
        int db = b - nConv;
        if (db == 0 && tid < 8) red[tid] = 0.f;
        if (tid < 4) { S_im[db * 4 + tid] = 0.f; S_tt[db * 4 + tid] = 0.f; }
        int row  = db * 4 + (tid >> 6);
        int lane = tid & 63;
        const float* a = rim + (size_t)row * D;
        const float* c2 = rtt + (size_t)row * D;
        float s = 0.f;
        for (int k = lane * 4; k < D; k += 256) {
            float4 av = *(const float4*)(a + k);
            float4 cv = *(const float4*)(c2 + k);
            s += av.x * cv.x + av.y * cv.y + av.z * cv.z + av.w * cv.w;
        }
        #pragma unroll
        for (int m2 = 1; m2 < 64; m2 <<= 1) s += __shfl_xor(s, m2, 64);
        if (lane == 0) diag[row] = s;
    }
}

// MX-scaled fp8 GEMM -- m148 replica: 128x128 tile, 4 waves (2x2 of 64x64),
// BK=128, SINGLE-buffered 32 KiB LDS, plain __syncthreads() 2-barrier loop,
// compiler-managed waits. Occupancy ~3-4 blocks/CU provides the implicit
// cross-block latency overlap (m97/m148 regime: one block drains its DMA
// while another computes). Grid (Bn/128, Bn/128, 2) = 2048 blocks.
// + exp + masked row-sum epilogue.
__global__ __launch_bounds__(256) void gemm_expsum(
    const unsigned char* __restrict__ A0, const unsigned char* __restrict__ B0,
    float* __restrict__ S0,
    const unsigned char* __restrict__ A1, const unsigned char* __restrict__ B1,
    float* __restrict__ S1,
    const float* __restrict__ logit_scale, const int* __restrict__ offset,
    int Bn, int D)
{
    __shared__ unsigned char As[16384];
    __shared__ unsigned char Bs[16384];

    const int z = blockIdx.z;
    const unsigned char* A = z ? A1 : A0;
    const unsigned char* B = z ? B1 : B0;
    float* S = z ? S1 : S0;

    const int tid  = threadIdx.x;
    const int wave = tid >> 6;
    const int lane = tid & 63;
    const int lo   = lane & 15;
    const int qd   = lane >> 4;
    const int wm   = wave >> 1;              // 0..1  (M half, 64 rows)
    const int wn   = wave & 1;               // 0..1  (N half, 64 cols)
    const int offA = ((2 * qd) ^ (lo & 7)) * 16;   // first 16-B slot

    // XCD-bijective swizzle per z-plane (nwg = 1024, % 8 == 0).
    const int nx  = gridDim.x;
    const int nwg = nx * gridDim.y;
    int wg = blockIdx.y * nx + blockIdx.x;
    int swz = ((nwg & 7) == 0) ? ((wg & 7) * (nwg >> 3) + (wg >> 3)) : wg;
    const int by = swz / nx;
    const int bx = swz - by * nx;

    const int kTiles = D >> 7;
    const unsigned char* Atile = A + (size_t)by * kTiles * 16384;
    const unsigned char* Btile = B + (size_t)bx * kTiles * 16384;

    f32x4 acc[4][4];
    #pragma unroll
    for (int i = 0; i < 4; ++i)
        #pragma unroll
        for (int j = 0; j < 4; ++j)
            acc[i][j] = (f32x4){0.f, 0.f, 0.f, 0.f};

    // per-lane LDS fragment bases (r&7 == lo&7 for all ti/tj)
    const int aOff0 = (wm * 64 + lo) * 128 + offA;   // + ti*2048
    const int bOff0 = (wn * 64 + lo) * 128 + offA;   // + tj*2048

    for (int kb = 0; kb < kTiles; ++kb) {
        // Stage A+B tile kb (16 KB each): 4 waves x 4 DMA x 1 KB per matrix.
        {
            const unsigned char* Ag = Atile + (size_t)kb * 16384
                                    + wave * 4096 + lane * 16;
            const unsigned char* Bg = Btile + (size_t)kb * 16384
                                    + wave * 4096 + lane * 16;
            #pragma unroll
            for (int q = 0; q < 4; ++q) {
                __builtin_amdgcn_global_load_lds(
                    (const AS_GLOBAL unsigned int*)(Ag + q * 1024),
                    (AS_LDS unsigned int*)&As[wave * 4096 + q * 1024],
                    16, 0, 0);
                __builtin_amdgcn_global_load_lds(
                    (const AS_GLOBAL unsigned int*)(Bg + q * 1024),
                    (AS_LDS unsigned int*)&Bs[wave * 4096 + q * 1024],
                    16, 0, 0);
            }
        }
        __syncthreads();           // compiler drains vmcnt before barrier

        i32x8 bq[4];
        #pragma unroll
        for (int tj = 0; tj < 4; ++tj) {
            const int ba = bOff0 + tj * 2048;
            union { int4 h[2]; i32x8 v; } u;
            u.h[0] = *(const int4*)&Bs[ba];
            u.h[1] = *(const int4*)&Bs[ba ^ 16];
            bq[tj] = u.v;
        }
        #pragma unroll
        for (int ti = 0; ti < 4; ++ti) {
            const int aa = aOff0 + ti * 2048;
            union { int4 h[2]; i32x8 v; } u;
            u.h[0] = *(const int4*)&As[aa];
            u.h[1] = *(const int4*)&As[aa ^ 16];
            i32x8 af = u.v;
            #pragma unroll
            for (int tj = 0; tj < 4; ++tj)
                acc[ti][tj] = __builtin_amdgcn_mfma_scale_f32_16x16x128_f8f6f4(
                    af, bq[tj], acc[ti][tj],
                    0, 0,          // cbsz=fp8(e4m3), blgp=fp8(e4m3)
                    0, 127,        // scale A: E8M0 127 = x1.0
                    0, 127);       // scale B
        }
        __syncthreads();           // done with LDS before next stage
    }

    const float ls = logit_scale[0];
    const int offs = offset[0];
    const int rowBase = by * 128 + wm * 64;
    const int colBase = bx * 128 + wn * 64;
    #pragma unroll
    for (int ti = 0; ti < 4; ++ti) {
        #pragma unroll
        for (int r = 0; r < 4; ++r) {
            int gi = rowBase + 16 * ti + 4 * qd + r;     // C/D row=quad*4+reg
            float rs = 0.f;
            #pragma unroll
            for (int tj = 0; tj < 4; ++tj) {
                int gj = colBase + 16 * tj + lo;         // C/D col=lane&15
                float e = __expf(ls * acc[ti][tj][r]);
                if (gj == gi + offs) e = 0.f;            // shifted diagonal
                rs += e;
            }
            #pragma unroll
            for (int m = 1; m < 16; m <<= 1) rs += __shfl_xor(rs, m, 64);
            if (lo == 0) atomicAdd(&S[gi], rs);
        }
    }
}

// 32-block reduction; last block (ticket) computes the scalar loss.
__global__ __launch_bounds__(256) void final_kernel(
    const float* __restrict__ S_im, const float* __restrict__ S_tt,
    const float* __restrict__ diag,
    const float* __restrict__ ru_im, const float* __restrict__ ru_tt,
    const float* __restrict__ l1_im, const float* __restrict__ l1_tt,
    const float* __restrict__ u_im,  const float* __restrict__ u_tt,
    const float* __restrict__ logit_scale, float* __restrict__ red,
    float* __restrict__ out, int Bn)
{
    const float ls = logit_scale[0];
    const float inv_rw = 1.0f / (float)(Bn - 1);
    const int gid = blockIdx.x * 256 + threadIdx.x;
    const int stride = gridDim.x * 256;
    float pg = 0.f, lg = 0.f;
    for (int i = gid; i < Bn; i += stride) {
        float p1 = l1_im[i] / (u_im[i] + EPSF) + l1_tt[i] / (u_tt[i] + EPSF);
        float dd = expf(-ls * diag[i]);
        float p2 = dd * S_im[i] * inv_rw / (ru_im[i] + EPSF)
                 + dd * S_tt[i] * inv_rw / (ru_tt[i] + EPSF);
        pg += p1 + p2;
        lg += logf(u_im[i]) + logf(u_tt[i]);
    }
    __shared__ float sp[256], sl[256];
    sp[threadIdx.x] = pg; sl[threadIdx.x] = lg;
    __syncthreads();
    for (int s = 128; s > 0; s >>= 1) {
        if (threadIdx.x < s) { sp[threadIdx.x] += sp[threadIdx.x + s];
                               sl[threadIdx.x] += sl[threadIdx.x + s]; }
        __syncthreads();
    }
    if (threadIdx.x == 0) {
        atomicAdd(&red[0], sp[0]);
        atomicAdd(&red[1], sl[0]);
        __threadfence();
        int t = atomicAdd((int*)&red[2], 1);
        if (t == gridDim.x - 1) {
            float pgSum = atomicAdd(&red[0], 0.f);
            float lgSum = atomicAdd(&red[1], 0.f);
            float loss = ((pgSum / (float)Bn) * 0.5f) / ls
                       + RHOF / ls
                       + (lgSum / (float)Bn) * 0.5f / ls;
            out[0] = loss;
        }
    }
}

extern "C" void kernel_launch(void* const* d_in, const int* in_sizes, int n_in,
                              void* d_out, int out_size, void* d_ws, size_t ws_size,
                              hipStream_t stream) {
    const float* im    = (const float*)d_in[0];
    const float* tt    = (const float*)d_in[1];
    const float* rim   = (const float*)d_in[2];
    const float* rtt   = (const float*)d_in[3];
    const float* ru_im = (const float*)d_in[4];
    const float* ru_tt = (const float*)d_in[5];
    const float* l1_im = (const float*)d_in[6];
    const float* l1_tt = (const float*)d_in[7];
    const float* u_im  = (const float*)d_in[8];
    const float* u_tt  = (const float*)d_in[9];
    const float* lsc   = (const float*)d_in[10];
    const int*   offs  = (const int*)d_in[11];

    const int Bn = in_sizes[4];          // 4096
    const int D  = in_sizes[0] / Bn;     // 1024
    const int rpb = 4096 / D;            // rows per conversion block
    const int bpm = Bn / rpb;            // conversion blocks per matrix

    char* base = (char*)d_ws;
    float* S_im = (float*)base;
    float* S_tt = S_im + Bn;
    float* diag = S_tt + Bn;
    float* red  = diag + Bn;             // [0]=pg, [1]=lg, [2]=ticket
    const size_t headBytes = (((size_t)(3 * Bn + 8) * sizeof(float)) + 255) & ~(size_t)255;
    const size_t matBytes  = (size_t)Bn * D;          // fp8: 1 B/elem
    unsigned char* buf0 = (unsigned char*)(base + headBytes);
    unsigned char* bRim = buf0;
    unsigned char* bTt  = buf0 + matBytes;
    unsigned char* bRtt = buf0 + 2 * matBytes;
    unsigned char* bIm  = buf0 + 3 * matBytes;

    prep_fp8<<<4 * bpm + Bn / 4, 256, 0, stream>>>(
        im, tt, rim, rtt, bIm, bTt, bRim, bRtt, S_im, S_tt, diag, red, D, bpm);

    dim3 ggrid(Bn / 128, Bn / 128, 2);
    gemm_expsum<<<ggrid, 256, 0, stream>>>(bRim, bTt, S_im, bRtt, bIm, S_tt,
                                           lsc, offs, Bn, D);

    final_kernel<<<32, 256, 0, stream>>>(S_im, S_tt, diag, ru_im, ru_tt,
                                         l1_im, l1_tt, u_im, u_tt, lsc,
                                         red, (float*)d_out, Bn);
}